// Round 3
// baseline (287.716 us; speedup 1.0000x reference)
//
#include <hip/hip_runtime.h>
#include <cfloat>
#include <math.h>

#define BINS 64
#define NELEM (192*224*192)       // 8,257,536 per batch sample (C=1)
#define N4    (NELEM/4)           // 2,064,384 float4 per slice
#define NB 2
#define HIST_OFF 16               // ws u32 index where histograms start
#define BLK 256
#define GBLK 1024                 // blocks per batch-slice -> 2048 total (8/CU)

// ---- monotonic float<->uint key (unsigned ascending == float ascending) ----
__device__ __forceinline__ unsigned fkey(float f){
    unsigned u = __float_as_uint(f);
    return (u & 0x80000000u) ? ~u : (u | 0x80000000u);
}
__device__ __forceinline__ float funkey(unsigned k){
    unsigned u = (k & 0x80000000u) ? (k ^ 0x80000000u) : ~k;
    return __uint_as_float(u);
}

// ws layout (u32): [0..15] minmax keys: b*4 + {fmin,fmax,wmin,wmax}
//                  [16..16+NB*4096) joint histograms
__global__ void k_init(unsigned* ws){
    int i = blockIdx.x * 256 + threadIdx.x;
    if (i < 16) ws[i] = ((i & 1) == 0) ? 0xFFFFFFFFu : 0u;
    if (i < NB * BINS * BINS) ws[HIST_OFF + i] = 0u;
}

__device__ __forceinline__ void mm4(const float4& v, float& mn, float& mx){
    mn = fminf(mn, fminf(fminf(v.x, v.y), fminf(v.z, v.w)));
    mx = fmaxf(mx, fmaxf(fmaxf(v.x, v.y), fmaxf(v.z, v.w)));
}

// grid (GBLK, NB): y = batch. Persistent grid-stride, unroll-2 (4 loads in flight).
__global__ __launch_bounds__(BLK) void k_minmax(const float* __restrict__ F,
                                                const float* __restrict__ W,
                                                unsigned* ws){
    const int b = blockIdx.y;
    const float4* F4 = (const float4*)(F + (size_t)b * NELEM);
    const float4* W4 = (const float4*)(W + (size_t)b * NELEM);
    const int stride = GBLK * BLK;            // 262144
    float fmn = FLT_MAX, fmx = -FLT_MAX, wmn = FLT_MAX, wmx = -FLT_MAX;

    int i = blockIdx.x * BLK + threadIdx.x;
    while (i + stride < N4){
        float4 a0 = F4[i], c0 = W4[i];
        float4 a1 = F4[i + stride], c1 = W4[i + stride];
        mm4(a0, fmn, fmx); mm4(a1, fmn, fmx);
        mm4(c0, wmn, wmx); mm4(c1, wmn, wmx);
        i += 2 * stride;
    }
    if (i < N4){
        float4 a0 = F4[i], c0 = W4[i];
        mm4(a0, fmn, fmx); mm4(c0, wmn, wmx);
    }

    for (int off = 32; off; off >>= 1){
        fmn = fminf(fmn, __shfl_down(fmn, off));
        fmx = fmaxf(fmx, __shfl_down(fmx, off));
        wmn = fminf(wmn, __shfl_down(wmn, off));
        wmx = fmaxf(wmx, __shfl_down(wmx, off));
    }
    __shared__ float s[4][4];
    int wave = threadIdx.x >> 6;
    if ((threadIdx.x & 63) == 0){
        s[wave][0] = fmn; s[wave][1] = fmx; s[wave][2] = wmn; s[wave][3] = wmx;
    }
    __syncthreads();
    if (threadIdx.x == 0){
        float a0 = s[0][0], a1 = s[0][1], a2 = s[0][2], a3 = s[0][3];
        for (int wv = 1; wv < 4; ++wv){
            a0 = fminf(a0, s[wv][0]); a1 = fmaxf(a1, s[wv][1]);
            a2 = fminf(a2, s[wv][2]); a3 = fmaxf(a3, s[wv][3]);
        }
        atomicMin(&ws[b*4+0], fkey(a0));
        atomicMax(&ws[b*4+1], fkey(a1));
        atomicMin(&ws[b*4+2], fkey(a2));
        atomicMax(&ws[b*4+3], fkey(a3));
    }
}

__device__ __forceinline__ void bin4(const float4& fa, const float4& wa,
                                     float fmn, float wmn, float fsc, float wsc,
                                     unsigned* h){
    float fv[4] = {fa.x, fa.y, fa.z, fa.w};
    float wv[4] = {wa.x, wa.y, wa.z, wa.w};
    #pragma unroll
    for (int j = 0; j < 4; ++j){
        int fi = (int)((fv[j] - fmn) * fsc);
        int wi = (int)((wv[j] - wmn) * wsc);
        fi = min(max(fi, 0), 63);
        wi = min(max(wi, 0), 63);
        atomicAdd(&h[fi * BINS + wi], 1u);
    }
}

// grid (GBLK, NB): y = batch. Persistent grid-stride, unroll-2.
__global__ __launch_bounds__(BLK) void k_hist(const float* __restrict__ F,
                                              const float* __restrict__ W,
                                              unsigned* ws){
    const int b = blockIdx.y;
    __shared__ unsigned h[BINS * BINS];
    for (int i = threadIdx.x; i < BINS * BINS; i += BLK) h[i] = 0u;

    const float fmn = funkey(ws[b*4+0]);
    const float fmx = funkey(ws[b*4+1]);
    const float wmn = funkey(ws[b*4+2]);
    const float wmx = funkey(ws[b*4+3]);
    const float fsc = 63.0f / (fmx - fmn + 1e-10f);
    const float wsc = 63.0f / (wmx - wmn + 1e-10f);

    const float4* F4 = (const float4*)(F + (size_t)b * NELEM);
    const float4* W4 = (const float4*)(W + (size_t)b * NELEM);
    const int stride = GBLK * BLK;
    __syncthreads();

    int i = blockIdx.x * BLK + threadIdx.x;
    while (i + stride < N4){
        float4 a0 = F4[i], c0 = W4[i];
        float4 a1 = F4[i + stride], c1 = W4[i + stride];
        bin4(a0, c0, fmn, wmn, fsc, wsc, h);
        bin4(a1, c1, fmn, wmn, fsc, wsc, h);
        i += 2 * stride;
    }
    if (i < N4){
        float4 a0 = F4[i], c0 = W4[i];
        bin4(a0, c0, fmn, wmn, fsc, wsc, h);
    }

    __syncthreads();
    unsigned* gh = ws + HIST_OFF + b * BINS * BINS;
    for (int i2 = threadIdx.x; i2 < BINS * BINS; i2 += BLK){
        unsigned v = h[i2];
        if (v) atomicAdd(&gh[i2], v);
    }
}

__device__ double block_sum256(double v, double* sred){
    int t = threadIdx.x;
    sred[t] = v; __syncthreads();
    for (int off = 128; off; off >>= 1){
        if (t < off) sred[t] += sred[t + off];
        __syncthreads();
    }
    double r = sred[0]; __syncthreads();
    return r;
}

__global__ void k_final(const float* __restrict__ pa, const float* __restrict__ ta,
                        const unsigned* __restrict__ ws, float* __restrict__ out){
    __shared__ double sred[256];
    const unsigned* hist = ws + HIST_OFF;
    const float fN = (float)NELEM;   // exact in f32 (< 2^24)
    double loss_sim = 0.0;
    for (int b = 0; b < NB; ++b){
        const unsigned* H = hist + b * BINS * BINS;
        double hj_p = 0.0;
        for (int i = threadIdx.x; i < BINS * BINS; i += 256){
            float p = (float)H[i] / fN;
            hj_p += (double)(p * logf(p + 1e-10f));
        }
        double hj = -block_sum256(hj_p, sred);
        double hf_p = 0.0, hw_p = 0.0;
        if (threadIdx.x < BINS){
            int r = threadIdx.x;
            unsigned cf = 0, cw = 0;
            for (int j = 0; j < BINS; ++j){
                cf += H[r * BINS + j];
                cw += H[j * BINS + r];
            }
            float pf = (float)cf / fN, pw = (float)cw / fN;
            hf_p = (double)(pf * logf(pf + 1e-10f));
            hw_p = (double)(pw * logf(pw + 1e-10f));
        }
        double hf = -block_sum256(hf_p, sred);
        double hw = -block_sum256(hw_p, sred);
        double mi  = hf + hw - hj;
        double nmi = 2.0 * mi / (hf + hw + 1e-10);
        loss_sim += -nmi;
    }
    loss_sim /= (double)NB;
    if (threadIdx.x == 0){
        double a = 0.0;
        for (int i = 0; i < 24; ++i){
            double d = (double)pa[i] - (double)ta[i];
            a += d * d;
        }
        a /= 24.0;
        out[0] = (float)(a + loss_sim);
    }
}

extern "C" void kernel_launch(void* const* d_in, const int* in_sizes, int n_in,
                              void* d_out, int out_size, void* d_ws, size_t ws_size,
                              hipStream_t stream) {
    const float* pa = (const float*)d_in[0];
    const float* ta = (const float*)d_in[1];
    const float* F  = (const float*)d_in[2];
    const float* W  = (const float*)d_in[3];
    float* out = (float*)d_out;
    unsigned* ws = (unsigned*)d_ws;

    k_init<<<33, 256, 0, stream>>>(ws);
    k_minmax<<<dim3(GBLK, NB), BLK, 0, stream>>>(F, W, ws);
    k_hist<<<dim3(GBLK, NB), BLK, 0, stream>>>(F, W, ws);
    k_final<<<1, 256, 0, stream>>>(pa, ta, ws, out);
}

// Round 4
// 230.464 us; speedup vs baseline: 1.2484x; 1.2484x over previous
//
#include <hip/hip_runtime.h>
#include <cfloat>
#include <math.h>

#define BINS 64
#define NELEM (192*224*192)       // 8,257,536 per batch sample (C=1)
#define N4    (NELEM/4)           // 2,064,384 float4 per slice
#define NB 2
#define HIST_OFF 16               // ws u32 index where histograms start

// ---- monotonic float<->uint key (unsigned ascending == float ascending) ----
__device__ __forceinline__ unsigned fkey(float f){
    unsigned u = __float_as_uint(f);
    return (u & 0x80000000u) ? ~u : (u | 0x80000000u);
}
__device__ __forceinline__ float funkey(unsigned k){
    unsigned u = (k & 0x80000000u) ? (k ^ 0x80000000u) : ~k;
    return __uint_as_float(u);
}

// ws layout (u32): [0..15] minmax keys: b*4 + {fmin,fmax,wmin,wmax}
//                  [16..16+NB*4096) joint histograms
__global__ void k_init(unsigned* ws){
    int i = blockIdx.x * 256 + threadIdx.x;
    if (i < 16) ws[i] = ((i & 1) == 0) ? 0xFFFFFFFFu : 0u;
    if (i < NB * BINS * BINS) ws[HIST_OFF + i] = 0u;
}

// grid (512, NB): y = batch — exact R1 structure (empirically fastest: 78 us)
__global__ void k_minmax(const float* __restrict__ F, const float* __restrict__ W,
                         unsigned* ws){
    const int b = blockIdx.y;
    const float4* F4 = (const float4*)(F + (size_t)b * NELEM);
    const float4* W4 = (const float4*)(W + (size_t)b * NELEM);
    float fmn = FLT_MAX, fmx = -FLT_MAX, wmn = FLT_MAX, wmx = -FLT_MAX;
    for (int i = blockIdx.x * blockDim.x + threadIdx.x; i < N4;
         i += gridDim.x * blockDim.x){
        float4 a = F4[i], c = W4[i];
        fmn = fminf(fmn, fminf(fminf(a.x, a.y), fminf(a.z, a.w)));
        fmx = fmaxf(fmx, fmaxf(fmaxf(a.x, a.y), fmaxf(a.z, a.w)));
        wmn = fminf(wmn, fminf(fminf(c.x, c.y), fminf(c.z, c.w)));
        wmx = fmaxf(wmx, fmaxf(fmaxf(c.x, c.y), fmaxf(c.z, c.w)));
    }
    for (int off = 32; off; off >>= 1){
        fmn = fminf(fmn, __shfl_down(fmn, off));
        fmx = fmaxf(fmx, __shfl_down(fmx, off));
        wmn = fminf(wmn, __shfl_down(wmn, off));
        wmx = fmaxf(wmx, __shfl_down(wmx, off));
    }
    __shared__ float s[4][4];
    int wave = threadIdx.x >> 6;
    if ((threadIdx.x & 63) == 0){
        s[wave][0] = fmn; s[wave][1] = fmx; s[wave][2] = wmn; s[wave][3] = wmx;
    }
    __syncthreads();
    if (threadIdx.x == 0){
        float a0 = s[0][0], a1 = s[0][1], a2 = s[0][2], a3 = s[0][3];
        for (int wv = 1; wv < 4; ++wv){
            a0 = fminf(a0, s[wv][0]); a1 = fmaxf(a1, s[wv][1]);
            a2 = fminf(a2, s[wv][2]); a3 = fmaxf(a3, s[wv][3]);
        }
        atomicMin(&ws[b*4+0], fkey(a0));
        atomicMax(&ws[b*4+1], fkey(a1));
        atomicMin(&ws[b*4+2], fkey(a2));
        atomicMax(&ws[b*4+3], fkey(a3));
    }
}

// grid (256, NB): y = batch — exact R1 structure
__global__ void k_hist(const float* __restrict__ F, const float* __restrict__ W,
                       unsigned* ws){
    const int b = blockIdx.y;
    __shared__ unsigned h[BINS * BINS];
    for (int i = threadIdx.x; i < BINS * BINS; i += blockDim.x) h[i] = 0u;
    __syncthreads();
    const float fmn = funkey(ws[b*4+0]);
    const float fmx = funkey(ws[b*4+1]);
    const float wmn = funkey(ws[b*4+2]);
    const float wmx = funkey(ws[b*4+3]);
    const float fden = fmx - fmn + 1e-10f;   // exact ref f32 arithmetic
    const float wden = wmx - wmn + 1e-10f;
    const float4* F4 = (const float4*)(F + (size_t)b * NELEM);
    const float4* W4 = (const float4*)(W + (size_t)b * NELEM);
    for (int i = blockIdx.x * blockDim.x + threadIdx.x; i < N4;
         i += gridDim.x * blockDim.x){
        float4 a = F4[i], c = W4[i];
        float fa[4] = {a.x, a.y, a.z, a.w};
        float wa[4] = {c.x, c.y, c.z, c.w};
        #pragma unroll
        for (int k = 0; k < 4; ++k){
            int fi = (int)((fa[k] - fmn) / fden * 63.0f);
            int wi = (int)((wa[k] - wmn) / wden * 63.0f);
            fi = min(max(fi, 0), 63);
            wi = min(max(wi, 0), 63);
            atomicAdd(&h[fi * BINS + wi], 1u);
        }
    }
    __syncthreads();
    unsigned* gh = ws + HIST_OFF + b * BINS * BINS;
    for (int i = threadIdx.x; i < BINS * BINS; i += blockDim.x){
        unsigned v = h[i];
        if (v) atomicAdd(&gh[i], v);
    }
}

__device__ double bsum1024(double v, double* sred){
    int t = threadIdx.x;
    sred[t] = v; __syncthreads();
    for (int off = 512; off; off >>= 1){
        if (t < off) sred[t] += sred[t + off];
        __syncthreads();
    }
    double r = sred[0]; __syncthreads();
    return r;
}

// 1 block x 1024 threads — parallel epilogue (was the hidden ~75 us cost)
__global__ __launch_bounds__(1024) void k_final(const float* __restrict__ pa,
                                                const float* __restrict__ ta,
                                                const unsigned* __restrict__ ws,
                                                float* __restrict__ out){
    __shared__ unsigned hs[BINS * BINS];      // 16 KB
    __shared__ unsigned rowc[BINS], colc[BINS];
    __shared__ double sred[1024];             // 8 KB
    const unsigned* hist = ws + HIST_OFF;
    const float fN = (float)NELEM;            // exact in f32 (< 2^24)
    const int t = threadIdx.x;
    double loss_sim = 0.0;

    for (int b = 0; b < NB; ++b){
        const unsigned* H = hist + b * BINS * BINS;
        // stage histogram in LDS (4 cells/thread)
        #pragma unroll
        for (int k = 0; k < 4; ++k) hs[t + k * 1024] = H[t + k * 1024];
        __syncthreads();
        // exact integer marginals
        if (t < BINS){
            unsigned cf = 0;
            for (int j = 0; j < BINS; ++j) cf += hs[t * BINS + j];
            rowc[t] = cf;
        } else if (t < 2 * BINS){
            int r = t - BINS;
            unsigned cw = 0;
            for (int j = 0; j < BINS; ++j) cw += hs[j * BINS + r];
            colc[r] = cw;
        }
        __syncthreads();
        // joint entropy: 4 cells/thread
        double hj_p = 0.0;
        #pragma unroll
        for (int k = 0; k < 4; ++k){
            float p = (float)hs[t + k * 1024] / fN;
            hj_p += (double)(p * __logf(p + 1e-10f));
        }
        double hj = -bsum1024(hj_p, sred);
        // S = h_f + h_w in one reduction (mi & nmi only need S and hj)
        double s_p = 0.0;
        if (t < BINS){
            float pf = (float)rowc[t] / fN;
            s_p = (double)(pf * __logf(pf + 1e-10f));
        } else if (t < 2 * BINS){
            float pw = (float)colc[t - BINS] / fN;
            s_p = (double)(pw * __logf(pw + 1e-10f));
        }
        double S = -bsum1024(s_p, sred);
        double mi  = S - hj;
        double nmi = 2.0 * mi / (S + 1e-10);
        loss_sim += -nmi;
        __syncthreads();
    }
    if (t == 0){
        loss_sim /= (double)NB;
        double a = 0.0;
        for (int i = 0; i < 24; ++i){
            double d = (double)pa[i] - (double)ta[i];
            a += d * d;
        }
        a /= 24.0;
        out[0] = (float)(a + loss_sim);
    }
}

extern "C" void kernel_launch(void* const* d_in, const int* in_sizes, int n_in,
                              void* d_out, int out_size, void* d_ws, size_t ws_size,
                              hipStream_t stream) {
    const float* pa = (const float*)d_in[0];
    const float* ta = (const float*)d_in[1];
    const float* F  = (const float*)d_in[2];
    const float* W  = (const float*)d_in[3];
    float* out = (float*)d_out;
    unsigned* ws = (unsigned*)d_ws;

    k_init<<<33, 256, 0, stream>>>(ws);
    k_minmax<<<dim3(512, NB), 256, 0, stream>>>(F, W, ws);
    k_hist<<<dim3(256, NB), 256, 0, stream>>>(F, W, ws);
    k_final<<<1, 1024, 0, stream>>>(pa, ta, ws, out);
}

// Round 5
// 220.346 us; speedup vs baseline: 1.3058x; 1.0459x over previous
//
#include <hip/hip_runtime.h>
#include <cfloat>
#include <math.h>

#define BINS 64
#define NELEM (192*224*192)       // 8,257,536 per batch sample (C=1)
#define N4    (NELEM/4)           // 2,064,384 float4 per slice
#define NB 2
#define HIST_OFF 16               // ws u32 index where histograms start
#define BLK 256

// ws layout (u32): [0..7]  minmax keys: b*4 + {fmin,fmax,wmin,wmax}
//                  [8..11] float accums: {hj_b0, hj_b1, (unused), (unused)}
//                  [16..16+NB*4096) joint histograms

__device__ __forceinline__ unsigned fkey(float f){
    unsigned u = __float_as_uint(f);
    return (u & 0x80000000u) ? ~u : (u | 0x80000000u);
}
__device__ __forceinline__ float funkey(unsigned k){
    unsigned u = (k & 0x80000000u) ? (k ^ 0x80000000u) : ~k;
    return __uint_as_float(u);
}

__global__ void k_init(unsigned* ws){
    int i = blockIdx.x * 256 + threadIdx.x;
    if (i < 16) ws[i] = (i < 8) ? (((i & 1) == 0) ? 0xFFFFFFFFu : 0u) : 0u;
    if (i < NB * BINS * BINS) ws[HIST_OFF + i] = 0u;
}

__device__ __forceinline__ void mm4(const float4& v, float& mn, float& mx){
    mn = fminf(mn, fminf(fminf(v.x, v.y), fminf(v.z, v.w)));
    mx = fmaxf(mx, fmaxf(fmaxf(v.x, v.y), fmaxf(v.z, v.w)));
}

// grid (512, 4): y -> (arr = y>>1, b = y&1). ONE contiguous stream per block.
__global__ __launch_bounds__(BLK) void k_minmax(const float* __restrict__ F,
                                                const float* __restrict__ W,
                                                unsigned* ws){
    const int arr = blockIdx.y >> 1;
    const int b   = blockIdx.y & 1;
    const float4* S4 = (const float4*)((arr ? W : F) + (size_t)b * NELEM);
    const int STRIDE = 512 * BLK;             // 131072 float4 = 2 MB
    float mn = FLT_MAX, mx = -FLT_MAX;

    int i = blockIdx.x * BLK + threadIdx.x;
    for (; i + STRIDE < N4; i += 2 * STRIDE){
        float4 v0 = S4[i];
        float4 v1 = S4[i + STRIDE];
        mm4(v0, mn, mx); mm4(v1, mn, mx);
    }
    if (i < N4){ float4 v0 = S4[i]; mm4(v0, mn, mx); }

    for (int off = 32; off; off >>= 1){
        mn = fminf(mn, __shfl_down(mn, off));
        mx = fmaxf(mx, __shfl_down(mx, off));
    }
    __shared__ float s[4][2];
    int wave = threadIdx.x >> 6;
    if ((threadIdx.x & 63) == 0){ s[wave][0] = mn; s[wave][1] = mx; }
    __syncthreads();
    if (threadIdx.x == 0){
        float a0 = s[0][0], a1 = s[0][1];
        for (int wv = 1; wv < 4; ++wv){
            a0 = fminf(a0, s[wv][0]); a1 = fmaxf(a1, s[wv][1]);
        }
        const int slot = b * 4 + arr * 2;
        atomicMin(&ws[slot],     fkey(a0));
        atomicMax(&ws[slot + 1], fkey(a1));
    }
}

__device__ __forceinline__ void bin4(const float4& fa, const float4& wa,
                                     float fmn, float wmn, float fden, float wden,
                                     unsigned* h){
    float fv[4] = {fa.x, fa.y, fa.z, fa.w};
    float wv[4] = {wa.x, wa.y, wa.z, wa.w};
    #pragma unroll
    for (int j = 0; j < 4; ++j){
        int fi = (int)((fv[j] - fmn) / fden * 63.0f);
        int wi = (int)((wv[j] - wmn) / wden * 63.0f);
        fi = min(max(fi, 0), 63);
        wi = min(max(wi, 0), 63);
        atomicAdd(&h[fi * BINS + wi], 1u);
    }
}

// grid (256, NB): y = batch. Grid-stride, unroll-2 (4 loads in flight).
__global__ __launch_bounds__(BLK) void k_hist(const float* __restrict__ F,
                                              const float* __restrict__ W,
                                              unsigned* ws){
    const int b = blockIdx.y;
    __shared__ unsigned h[BINS * BINS];
    for (int i = threadIdx.x; i < BINS * BINS; i += BLK) h[i] = 0u;

    const float fmn = funkey(ws[b*4+0]);
    const float fmx = funkey(ws[b*4+1]);
    const float wmn = funkey(ws[b*4+2]);
    const float wmx = funkey(ws[b*4+3]);
    const float fden = fmx - fmn + 1e-10f;   // exact ref f32 arithmetic
    const float wden = wmx - wmn + 1e-10f;

    const float4* F4 = (const float4*)(F + (size_t)b * NELEM);
    const float4* W4 = (const float4*)(W + (size_t)b * NELEM);
    const int STRIDE = 256 * BLK;            // 65536 float4
    __syncthreads();

    int i = blockIdx.x * BLK + threadIdx.x;
    for (; i + STRIDE < N4; i += 2 * STRIDE){
        float4 a0 = F4[i];
        float4 c0 = W4[i];
        float4 a1 = F4[i + STRIDE];
        float4 c1 = W4[i + STRIDE];
        bin4(a0, c0, fmn, wmn, fden, wden, h);
        bin4(a1, c1, fmn, wmn, fden, wden, h);
    }
    if (i < N4){
        float4 a0 = F4[i], c0 = W4[i];
        bin4(a0, c0, fmn, wmn, fden, wden, h);
    }

    __syncthreads();
    unsigned* gh = ws + HIST_OFF + b * BINS * BINS;
    for (int i2 = threadIdx.x; i2 < BINS * BINS; i2 += BLK){
        unsigned v = h[i2];
        if (v) atomicAdd(&gh[i2], v);
    }
}

// grid 32 x 256: joint-entropy partial sums -> atomicAdd into ws[8+b] (float)
__global__ __launch_bounds__(BLK) void k_finalA(unsigned* ws){
    const int id = blockIdx.x * BLK + threadIdx.x;   // [0, 8192)
    const int b  = id >> 12;
    const float fN = (float)NELEM;
    float p = (float)ws[HIST_OFF + id] / fN;
    float v = p * __logf(p + 1e-10f);
    for (int off = 32; off; off >>= 1) v += __shfl_down(v, off);
    if ((threadIdx.x & 63) == 0)
        atomicAdd((float*)(ws + 8 + b), v);          // 128 atomics total
}

// 1 block x 256: marginals + combine + affine MSE
__global__ __launch_bounds__(BLK) void k_finalB(const float* __restrict__ pa,
                                                const float* __restrict__ ta,
                                                unsigned* ws, float* __restrict__ out){
    const int t = threadIdx.x;
    const unsigned* hist = ws + HIST_OFF;
    const float fN = (float)NELEM;
    // wave 0: rows b0 | wave 1: rows b1 | wave 2: cols b0 | wave 3: cols b1
    const int wave = t >> 6, lane = t & 63;
    const int b = wave & 1;
    unsigned c = 0;
    if (wave < 2){ const unsigned* H = hist + b * 4096 + lane * 64;
        for (int j = 0; j < 64; ++j) c += H[j]; }
    else { const unsigned* H = hist + b * 4096 + lane;
        for (int j = 0; j < 64; ++j) c += H[j * 64]; }
    float p = (float)c / fN;
    float v = p * __logf(p + 1e-10f);
    for (int off = 32; off; off >>= 1) v += __shfl_down(v, off);
    __shared__ float sw[4];
    if (lane == 0) sw[wave] = v;
    __syncthreads();
    if (t == 0){
        double loss_sim = 0.0;
        for (int bb = 0; bb < NB; ++bb){
            double S  = -((double)sw[bb] + (double)sw[2 + bb]);  // h_f + h_w
            double hj = -(double)((float*)(ws + 8))[bb];
            double mi = S - hj;
            double nmi = 2.0 * mi / (S + 1e-10);
            loss_sim += -nmi;
        }
        loss_sim /= (double)NB;
        double a = 0.0;
        for (int i = 0; i < 24; ++i){
            double d = (double)pa[i] - (double)ta[i];
            a += d * d;
        }
        a /= 24.0;
        out[0] = (float)(a + loss_sim);
    }
}

extern "C" void kernel_launch(void* const* d_in, const int* in_sizes, int n_in,
                              void* d_out, int out_size, void* d_ws, size_t ws_size,
                              hipStream_t stream) {
    const float* pa = (const float*)d_in[0];
    const float* ta = (const float*)d_in[1];
    const float* F  = (const float*)d_in[2];
    const float* W  = (const float*)d_in[3];
    float* out = (float*)d_out;
    unsigned* ws = (unsigned*)d_ws;

    k_init<<<33, 256, 0, stream>>>(ws);
    k_minmax<<<dim3(512, 4), BLK, 0, stream>>>(F, W, ws);
    k_hist<<<dim3(256, NB), BLK, 0, stream>>>(F, W, ws);
    k_finalA<<<32, BLK, 0, stream>>>(ws);
    k_finalB<<<1, BLK, 0, stream>>>(pa, ta, ws, out);
}